// Round 1
// baseline (137.966 us; speedup 1.0000x reference)
//
#include <hip/hip_runtime.h>

// TopkWeightClusterLoss: per element w, per-row scale s:
//   d2[l] = (|w| - s*q)^2, q in [-7..7]; top-4 largest; softmax; sum v*(1-sm)
// Algebraic reduction: top-4 distances are always a subset of
//   { a+7s, a+6s, a+5s, a+4s, |7s-a|, |6s-a| }  with a=|w|
// where the first four are already sorted descending. Insert the two |.|
// candidates with a 7-op min/max chain each -> exact top-4 in 14 ops.

#define BLOCK 256
#define GRID  4096
#define ROW_SHIFT_F4 10   // 4096 floats/row = 1024 float4/row (problem is fixed 4096x4096)

__global__ __launch_bounds__(BLOCK) void topk_loss_kernel(
    const float* __restrict__ weight,
    const float* __restrict__ scale,
    float* __restrict__ out, int n4)
{
    float acc = 0.f;
    const int stride = gridDim.x * blockDim.x;
    for (int i = blockIdx.x * blockDim.x + threadIdx.x; i < n4; i += stride) {
        const float4 w4 = reinterpret_cast<const float4*>(weight)[i];
        const int row = i >> ROW_SHIFT_F4;
        const float s  = scale[row];
        const float s7 = 7.f * s, s6 = 6.f * s, s5 = 5.f * s, s4 = 4.f * s;
        const float ws[4] = {w4.x, w4.y, w4.z, w4.w};
        #pragma unroll
        for (int j = 0; j < 4; ++j) {
            const float a = fabsf(ws[j]);
            // sorted-descending left candidates (negative-side centers)
            const float L0 = a + s7, L1 = a + s6, L2 = a + s5, L3 = a + s4;
            // the only right-side centers that can reach top-4
            const float r0 = fabsf(s7 - a), r1 = fabsf(s6 - a);
            // insert r0 into [L0..L3], keep top 4 (descending)
            float x  = r0;
            float t0 = fmaxf(L0, x); x = fminf(L0, x);
            float t1 = fmaxf(L1, x); x = fminf(L1, x);
            float t2 = fmaxf(L2, x); x = fminf(L2, x);
            float t3 = fmaxf(L3, x);
            // insert r1
            x = r1;
            const float u0 = fmaxf(t0, x); x = fminf(t0, x);
            const float u1 = fmaxf(t1, x); x = fminf(t1, x);
            const float u2 = fmaxf(t2, x); x = fminf(t2, x);
            const float u3 = fmaxf(t3, x);
            // squared distances; u's are nonneg descending, so v0 is the max
            const float v0 = u0*u0, v1 = u1*u1, v2 = u2*u2, v3 = u3*u3;
            // softmax with max-shift by v0 (e0 == 1)
            const float e1 = __expf(v1 - v0);
            const float e2 = __expf(v2 - v0);
            const float e3 = __expf(v3 - v0);
            const float Z   = 1.f + e1 + e2 + e3;
            const float dot = v0 + v1*e1 + v2*e2 + v3*e3;
            acc += (v0 + v1 + v2 + v3) - __fdividef(dot, Z);
        }
    }
    // wave (64-lane) shuffle reduction
    #pragma unroll
    for (int off = 32; off > 0; off >>= 1)
        acc += __shfl_down(acc, off, 64);
    __shared__ float lds[BLOCK / 64];
    const int lane = threadIdx.x & 63, wid = threadIdx.x >> 6;
    if (lane == 0) lds[wid] = acc;
    __syncthreads();
    if (threadIdx.x == 0) {
        float t = 0.f;
        #pragma unroll
        for (int w = 0; w < BLOCK / 64; ++w) t += lds[w];
        atomicAdd(out, t * (0.01f / 3.0f));   // COEFF / (TOPK-1)
    }
}

extern "C" void kernel_launch(void* const* d_in, const int* in_sizes, int n_in,
                              void* d_out, int out_size, void* d_ws, size_t ws_size,
                              hipStream_t stream) {
    const float* weight = (const float*)d_in[0];
    const float* scale  = (const float*)d_in[1];
    float* out = (float*)d_out;
    const int n4 = in_sizes[0] / 4;   // 4,194,304 float4
    hipMemsetAsync(d_out, 0, sizeof(float), stream);  // d_out is re-poisoned 0xAA each call
    topk_loss_kernel<<<GRID, BLOCK, 0, stream>>>(weight, scale, out, n4);
}

// Round 2
// 136.004 us; speedup vs baseline: 1.0144x; 1.0144x over previous
//
#include <hip/hip_runtime.h>

// TopkWeightClusterLoss: per element w (row r), s = scale[r]:
//   d2[l] = (|w| - s*q)^2, q in [-7..7]; top-4 largest; softmax; sum v*(1-sm)
// Exact algebraic reduction (verified: absmax 0.0 vs reference in R1):
// with a=|w|, top-4 of the 15 distances is a subset of
//   { a+7s, a+6s, a+5s, a+4s, |7s-a|, |6s-a| }
// where the first four are pre-sorted descending. Inserting x into a sorted
// quad [L0>=L1>=L2>=L3] is { max(L0,x), med3(x,L0,L1), med3(x,L1,L2),
// med3(x,L2,L3) } -> 4 ops per insertion via v_med3_f32.

#define BLOCK 256
#define GRID  4096
#define K_PER_THREAD 4              // 4 float4 = 16 elements / thread
#define ROW_SHIFT_F4 10             // 4096 floats/row = 1024 float4/row

__global__ __launch_bounds__(BLOCK) void topk_loss_kernel(
    const float4* __restrict__ w4p,
    const float* __restrict__ scale,
    float* __restrict__ out)
{
    const int tid    = blockIdx.x * BLOCK + threadIdx.x;
    const int stride = GRID * BLOCK;          // 1,048,576 float4

    // ---- issue all global loads up front (8 independent loads in flight) ----
    float4 w[K_PER_THREAD];
    float  sc[K_PER_THREAD];
    #pragma unroll
    for (int k = 0; k < K_PER_THREAD; ++k) {
        const int i = tid + k * stride;
        w[k]  = w4p[i];
        sc[k] = scale[i >> ROW_SHIFT_F4];
    }

    float acc = 0.f;
    #pragma unroll
    for (int k = 0; k < K_PER_THREAD; ++k) {
        const float s  = sc[k];
        const float s7 = 7.f * s, s6 = 6.f * s, s5 = 5.f * s, s4 = 4.f * s;
        const float ws[4] = {w[k].x, w[k].y, w[k].z, w[k].w};
        #pragma unroll
        for (int j = 0; j < 4; ++j) {
            const float a = fabsf(ws[j]);
            // sorted-descending left candidates
            const float L0 = a + s7, L1 = a + s6, L2 = a + s5, L3 = a + s4;
            // only right-side centers that can reach top-4
            const float r0 = fabsf(s7 - a), r1 = fabsf(s6 - a);
            // insert r0 (med3 insertion, list stays sorted descending)
            const float t0 = fmaxf(L0, r0);
            const float t1 = __builtin_amdgcn_fmed3f(r0, L0, L1);
            const float t2 = __builtin_amdgcn_fmed3f(r0, L1, L2);
            const float t3 = __builtin_amdgcn_fmed3f(r0, L2, L3);
            // insert r1
            const float u0 = fmaxf(t0, r1);
            const float u1 = __builtin_amdgcn_fmed3f(r1, t0, t1);
            const float u2 = __builtin_amdgcn_fmed3f(r1, t1, t2);
            const float u3 = __builtin_amdgcn_fmed3f(r1, t2, t3);
            // squared distances; descending, so v0 is the softmax max
            const float v0 = u0*u0, v1 = u1*u1, v2 = u2*u2, v3 = u3*u3;
            const float e1 = __expf(v1 - v0);
            const float e2 = __expf(v2 - v0);
            const float e3 = __expf(v3 - v0);
            const float Z   = 1.f + e1 + e2 + e3;
            const float dot = fmaf(v3, e3, fmaf(v2, e2, fmaf(v1, e1, v0)));
            const float sv  = (v0 + v1) + (v2 + v3);
            acc = (acc + sv) - dot * __frcp_rn(Z);
        }
    }

    // ---- wave (64-lane) shuffle reduction, then LDS, then one atomic ----
    #pragma unroll
    for (int off = 32; off > 0; off >>= 1)
        acc += __shfl_down(acc, off, 64);
    __shared__ float lds[BLOCK / 64];
    const int lane = threadIdx.x & 63, wid = threadIdx.x >> 6;
    if (lane == 0) lds[wid] = acc;
    __syncthreads();
    if (threadIdx.x == 0) {
        float t = 0.f;
        #pragma unroll
        for (int wq = 0; wq < BLOCK / 64; ++wq) t += lds[wq];
        atomicAdd(out, t * (0.01f / 3.0f));   // COEFF / (TOPK-1)
    }
}

extern "C" void kernel_launch(void* const* d_in, const int* in_sizes, int n_in,
                              void* d_out, int out_size, void* d_ws, size_t ws_size,
                              hipStream_t stream) {
    const float4* weight4 = (const float4*)d_in[0];
    const float*  scale   = (const float*)d_in[1];
    float* out = (float*)d_out;
    hipMemsetAsync(d_out, 0, sizeof(float), stream);  // d_out re-poisoned 0xAA each call
    topk_loss_kernel<<<GRID, BLOCK, 0, stream>>>(weight4, scale, out);
}

// Round 4
// 104.038 us; speedup vs baseline: 1.3261x; 1.3073x over previous
//
#include <hip/hip_runtime.h>

// TopkWeightClusterLoss, exact algebraic form (absmax 0.0 in R1/R2):
// with a=|w|, top-4 of the 15 squared distances is a subset of
//   { a+7s, a+6s, a+5s, a+4s, |7s-a|, |6s-a| } , left quad pre-sorted desc.
// med3 insertion of the two right candidates -> exact sorted top-4.
//
// R4 = R3 with the OOB fixed: total float4 = 4096*4096/4 = 4*S_F4 exactly,
// so each thread owns 4 tiles at stride S_F4 (R3 wrongly spanned 16*S_F4).
// Depth-1 software pipeline: prefetch tile m+1 while computing tile m
// (prefetched regs are live across the compute body -> cannot be sunk).
// Two-stage reduction via d_ws (no same-address atomics).

#define BLOCK 256
#define GRID  4096
#define S_F4  (GRID * BLOCK)   // 1,048,576 float4; array = exactly 4 * S_F4
#define TILES 4

__device__ __forceinline__ float elem_loss(float wv, float s7, float s6,
                                           float s5, float s4) {
    const float a  = fabsf(wv);
    const float L0 = a + s7, L1 = a + s6, L2 = a + s5, L3 = a + s4;
    const float r0 = fabsf(s7 - a), r1 = fabsf(s6 - a);
    const float t0 = fmaxf(L0, r0);
    const float t1 = __builtin_amdgcn_fmed3f(r0, L0, L1);
    const float t2 = __builtin_amdgcn_fmed3f(r0, L1, L2);
    const float t3 = __builtin_amdgcn_fmed3f(r0, L2, L3);
    const float u0 = fmaxf(t0, r1);
    const float u1 = __builtin_amdgcn_fmed3f(r1, t0, t1);
    const float u2 = __builtin_amdgcn_fmed3f(r1, t1, t2);
    const float u3 = __builtin_amdgcn_fmed3f(r1, t2, t3);
    const float v0 = u0*u0, v1 = u1*u1, v2 = u2*u2, v3 = u3*u3;
    const float e1 = __expf(v1 - v0);
    const float e2 = __expf(v2 - v0);
    const float e3 = __expf(v3 - v0);
    const float Z   = 1.f + e1 + e2 + e3;
    const float dot = fmaf(v3, e3, fmaf(v2, e2, fmaf(v1, e1, v0)));
    return ((v0 + v1) + (v2 + v3)) - __fdividef(dot, Z);
}

__device__ __forceinline__ float quad_loss(float4 w4, float s) {
    const float s7 = 7.f*s, s6 = 6.f*s, s5 = 5.f*s, s4 = 4.f*s;
    return (elem_loss(w4.x, s7, s6, s5, s4) + elem_loss(w4.y, s7, s6, s5, s4))
         + (elem_loss(w4.z, s7, s6, s5, s4) + elem_loss(w4.w, s7, s6, s5, s4));
}

__global__ __launch_bounds__(BLOCK) void partial_kernel(
    const float4* __restrict__ w,
    const float* __restrict__ scale,
    float* __restrict__ partial)
{
    const int tid   = blockIdx.x * BLOCK + threadIdx.x;   // [0, S_F4)
    const int rbase = tid >> 10;          // 1024 float4/row -> row in [0,1024)

    // ---- prologue: tile 0 ----
    float4 cw = w[tid];
    float  cs = scale[rbase];

    float acc = 0.f;
    #pragma unroll
    for (int m = 0; m < TILES; ++m) {
        float4 nw; float ns;
        if (m + 1 < TILES) {                      // prefetch tile m+1
            nw = w[tid + (m + 1) * S_F4];
            ns = scale[rbase + (m + 1) * 1024];
        }
        acc += quad_loss(cw, cs);                 // compute tile m
        if (m + 1 < TILES) { cw = nw; cs = ns; }
    }

    // ---- block reduction -> one plain store per block ----
    #pragma unroll
    for (int off = 32; off > 0; off >>= 1)
        acc += __shfl_down(acc, off, 64);
    __shared__ float lds[BLOCK / 64];
    const int lane = threadIdx.x & 63, wid = threadIdx.x >> 6;
    if (lane == 0) lds[wid] = acc;
    __syncthreads();
    if (threadIdx.x == 0) {
        float t = 0.f;
        #pragma unroll
        for (int q = 0; q < BLOCK / 64; ++q) t += lds[q];
        partial[blockIdx.x] = t;
    }
}

__global__ __launch_bounds__(1024) void reduce_kernel(
    const float* __restrict__ partial, float* __restrict__ out)
{
    float v = 0.f;
    #pragma unroll
    for (int k = 0; k < GRID / 1024; ++k)
        v += partial[threadIdx.x + k * 1024];
    #pragma unroll
    for (int off = 32; off > 0; off >>= 1)
        v += __shfl_down(v, off, 64);
    __shared__ float lds[16];
    const int lane = threadIdx.x & 63, wid = threadIdx.x >> 6;
    if (lane == 0) lds[wid] = v;
    __syncthreads();
    if (threadIdx.x == 0) {
        float t = 0.f;
        #pragma unroll
        for (int q = 0; q < 16; ++q) t += lds[q];
        out[0] = t * (0.01f / 3.0f);   // COEFF / (TOPK-1)
    }
}

extern "C" void kernel_launch(void* const* d_in, const int* in_sizes, int n_in,
                              void* d_out, int out_size, void* d_ws, size_t ws_size,
                              hipStream_t stream) {
    const float4* weight4 = (const float4*)d_in[0];
    const float*  scale   = (const float*)d_in[1];
    float* out     = (float*)d_out;
    float* partial = (float*)d_ws;          // 4096 floats = 16 KB scratch
    partial_kernel<<<GRID, BLOCK, 0, stream>>>(weight4, scale, partial);
    reduce_kernel<<<1, 1024, 0, stream>>>(partial, out);
}

// Round 5
// 99.209 us; speedup vs baseline: 1.3907x; 1.0487x over previous
//
#include <hip/hip_runtime.h>

// TopkWeightClusterLoss, exact algebraic form (absmax 0.0 since R1):
// with a=|w|, s>0, top-4 of the 15 squared distances (|w|-qs)^2, q=-7..7, is
// a subset of { a+7s, a+6s, a+5s, a+4s, |7s-a|, |6s-a| }, left quad sorted
// descending. Since |7s-a|,|6s-a| <= a+7s always, the top element is a+7s
// and each insertion is 3 ops (1 max + 2 med3).
//
// exp2-domain: all candidates pre-scaled by sqrt(log2 e) so v' = v*log2(e)
// feeds v_exp_f32 directly; one global *ln2 folded into the output constant.
//
// R5 structure: depth-2 software pipeline over the 4 per-thread tiles
// (2 loads in flight under every compute block), two-stage reduction via d_ws.

#define BLOCK 256
#define GRID  4096
#define S_F4  (GRID * BLOCK)   // 1,048,576 float4; weight = exactly 4 * S_F4
#define TILES 4
#define C_SQRT_LOG2E 1.2011224087864498f
#define LN2 0.69314718055994531f

__device__ __forceinline__ float elem_loss(float wv, float s7, float s6,
                                           float s5, float s4) {
    const float a  = fabsf(wv) * C_SQRT_LOG2E;     // scaled |w|
    const float L0 = a + s7, L1 = a + s6, L2 = a + s5, L3 = a + s4;
    const float r0 = fabsf(s7 - a);
    const float r1 = fabsf(s6 - a);
    // insert r0 into sorted [L0..L3]; r0 <= L0 so top slot is fixed
    const float t1 = fmaxf(r0, L1);
    const float t2 = __builtin_amdgcn_fmed3f(r0, L1, L2);
    const float t3 = __builtin_amdgcn_fmed3f(r0, L2, L3);
    // insert r1 (also <= L0)
    const float u1 = fmaxf(r1, t1);
    const float u2 = __builtin_amdgcn_fmed3f(r1, t1, t2);
    const float u3 = __builtin_amdgcn_fmed3f(r1, t2, t3);
    // squared distances (scaled by log2e); L0 is the max
    const float v0 = L0*L0, v1 = u1*u1, v2 = u2*u2, v3 = u3*u3;
    const float e1 = __builtin_amdgcn_exp2f(v1 - v0);
    const float e2 = __builtin_amdgcn_exp2f(v2 - v0);
    const float e3 = __builtin_amdgcn_exp2f(v3 - v0);
    const float Z   = 1.f + e1 + e2 + e3;
    const float dot = fmaf(v3, e3, fmaf(v2, e2, fmaf(v1, e1, v0)));
    const float sv  = (v0 + v1) + (v2 + v3);
    return fmaf(-dot, __builtin_amdgcn_rcpf(Z), sv);   // = log2e * elem_loss
}

__device__ __forceinline__ float quad_loss(float4 w4, float s) {
    const float sq = s * C_SQRT_LOG2E;
    const float s7 = 7.f*sq, s6 = 6.f*sq, s5 = 5.f*sq, s4 = 4.f*sq;
    return (elem_loss(w4.x, s7, s6, s5, s4) + elem_loss(w4.y, s7, s6, s5, s4))
         + (elem_loss(w4.z, s7, s6, s5, s4) + elem_loss(w4.w, s7, s6, s5, s4));
}

__global__ __launch_bounds__(BLOCK, 8) void partial_kernel(
    const float4* __restrict__ w,
    const float* __restrict__ scale,
    float* __restrict__ partial)
{
    const int tid   = blockIdx.x * BLOCK + threadIdx.x;   // [0, S_F4)
    const int rbase = tid >> 10;          // 1024 float4/row -> row in [0,1024)

    // ---- prologue: tiles 0 and 1 in flight ----
    float4 cw0 = w[tid];
    float  cs0 = scale[rbase];
    float4 cw1 = w[tid + S_F4];
    float  cs1 = scale[rbase + 1024];

    float acc = 0.f;
    #pragma unroll
    for (int m = 0; m < TILES; ++m) {
        float4 nw; float ns;
        if (m + 2 < TILES) {                      // prefetch tile m+2
            nw = w[tid + (m + 2) * S_F4];
            ns = scale[rbase + (m + 2) * 1024];
        }
        acc += quad_loss(cw0, cs0);               // compute tile m
        cw0 = cw1; cs0 = cs1;                     // rotate pipeline
        if (m + 2 < TILES) { cw1 = nw; cs1 = ns; }
    }

    // ---- block reduction -> one plain store per block ----
    #pragma unroll
    for (int off = 32; off > 0; off >>= 1)
        acc += __shfl_down(acc, off, 64);
    __shared__ float lds[BLOCK / 64];
    const int lane = threadIdx.x & 63, wid = threadIdx.x >> 6;
    if (lane == 0) lds[wid] = acc;
    __syncthreads();
    if (threadIdx.x == 0) {
        float t = 0.f;
        #pragma unroll
        for (int q = 0; q < BLOCK / 64; ++q) t += lds[q];
        partial[blockIdx.x] = t;
    }
}

__global__ __launch_bounds__(1024) void reduce_kernel(
    const float* __restrict__ partial, float* __restrict__ out)
{
    float v = 0.f;
    #pragma unroll
    for (int k = 0; k < GRID / 1024; ++k)
        v += partial[threadIdx.x + k * 1024];
    #pragma unroll
    for (int off = 32; off > 0; off >>= 1)
        v += __shfl_down(v, off, 64);
    __shared__ float lds[16];
    const int lane = threadIdx.x & 63, wid = threadIdx.x >> 6;
    if (lane == 0) lds[wid] = v;
    __syncthreads();
    if (threadIdx.x == 0) {
        float t = 0.f;
        #pragma unroll
        for (int q = 0; q < 16; ++q) t += lds[q];
        out[0] = t * (0.01f / 3.0f) * LN2;   // COEFF/(TOPK-1), undo log2e scale
    }
}

extern "C" void kernel_launch(void* const* d_in, const int* in_sizes, int n_in,
                              void* d_out, int out_size, void* d_ws, size_t ws_size,
                              hipStream_t stream) {
    const float4* weight4 = (const float4*)d_in[0];
    const float*  scale   = (const float*)d_in[1];
    float* out     = (float*)d_out;
    float* partial = (float*)d_ws;          // 4096 floats = 16 KB scratch
    partial_kernel<<<GRID, BLOCK, 0, stream>>>(weight4, scale, partial);
    reduce_kernel<<<1, 1024, 0, stream>>>(partial, out);
}